// Round 4
// baseline (218.491 us; speedup 1.0000x reference)
//
#include <hip/hip_runtime.h>
#include <math.h>

namespace {
constexpr int SG = 14;
constexpr int NIMG = 4096;
constexpr int NCELLS = NIMG * SG * SG;   // 802816 = 3136 blocks * 256
constexpr int CPB = 256;                 // cells per block
constexpr int STRIDE = 11;               // LDS floats per cell for box part (odd -> conflict-free)
constexpr float STEPF = 1.0f / 14.0f;
constexpr float EPSF = 1e-6f;
constexpr float L_COORD = 7.0f;
constexpr float L_NOOBJ = 0.2f;
constexpr float L_CLS = 1.5f;
constexpr float INV_N = 1.0f / 4096.0f;
constexpr float FOUR_OVER_PI2 = 4.0f / (float)(M_PI * M_PI);
}

struct Box { float x1, y1, x2, y2; };

__device__ __forceinline__ float iou_fn(const Box& a, const Box& b) {
  float ix1 = fmaxf(a.x1, b.x1);
  float iy1 = fmaxf(a.y1, b.y1);
  float ix2 = fminf(a.x2, b.x2);
  float iy2 = fminf(a.y2, b.y2);
  float inter = fmaxf(ix2 - ix1, 0.0f) * fmaxf(iy2 - iy1, 0.0f);
  float a1 = (a.x2 - a.x1) * (a.y2 - a.y1);
  float a2 = (b.x2 - b.x1) * (b.y2 - b.y1);
  return __fdividef(inter, a1 + a2 - inter + EPSF);
}

// BCE term for one element; clip(log, -100) is lower-only. __logf(0)=-inf -> clamps to -100.
__device__ __forceinline__ float bce_term(float pc, float tc) {
  const float lg   = fmaxf(__logf(pc), -100.0f);
  const float l1mp = fmaxf(__logf(1.0f - pc), -100.0f);
  return -(tc * lg + (1.0f - tc) * l1mp);
}

__global__ __launch_bounds__(256, 6) void yolo_loss_kernel(
    const float* __restrict__ pred, const float* __restrict__ tgt,
    float* __restrict__ out) {
  // Box-only staging (10 floats/cell/input, stride 11) + per-cell BCE accumulator.
  // Total 2*11264 + 1024 + 16 = 23568 B -> 6 blocks/CU (24 waves, 75% occupancy cap).
  __shared__ float bp[CPB * STRIDE];
  __shared__ float bt[CPB * STRIDE];
  __shared__ float bce[CPB];
  __shared__ float sdata[4];

  const int tid = threadIdx.x;

  // ---- issue ALL global loads up front (single latency exposure) ----
  // Sweep space: float2 #idx holds elems (2idx, 2idx+1); pairs never straddle
  // a cell (2idx+1 is odd, cell boundary 30c is even) and never straddle the
  // box/class split at elem 10 (even).
  const float2* P2 = reinterpret_cast<const float2*>(pred) + (size_t)blockIdx.x * (CPB * 15);
  const float2* T2 = reinterpret_cast<const float2*>(tgt)  + (size_t)blockIdx.x * (CPB * 15);
  float2 pv[15], tv[15];
#pragma unroll
  for (int j = 0; j < 15; ++j) {
    pv[j] = P2[j * 256 + tid];
    tv[j] = T2[j * 256 + tid];
  }

  bce[tid] = 0.0f;
  __syncthreads();   // guards bce init; global loads still in flight

  // ---- sweep pass: scatter box floats to LDS, fold class BCE into bce[c] ----
#pragma unroll
  for (int j = 0; j < 15; ++j) {
    const int idx = j * 256 + tid;      // float2 index within block
    const int c = idx / 15;             // local cell (magic-mul)
    const int e = 2 * idx - 30 * c;     // even element 0..28
    const float2 v = pv[j];
    const float2 u = tv[j];
    if (e < 10) {
      bp[c * STRIDE + e] = v.x; bp[c * STRIDE + e + 1] = v.y;
      bt[c * STRIDE + e] = u.x; bt[c * STRIDE + e + 1] = u.y;
    } else {
      const float s = bce_term(v.x, u.x) + bce_term(v.y, u.y);
      atomicAdd(&bce[c], s);            // ds_add_f32
    }
  }
  __syncthreads();

  // ---- per-cell part: thread tid <-> local cell tid ----
  float p[10], t[10];
#pragma unroll
  for (int k = 0; k < 10; ++k) {
    p[k] = bp[tid * STRIDE + k];        // stride 11: 2-way (free) bank aliasing
    t[k] = bt[tid * STRIDE + k];
  }

  const int cell = blockIdx.x * CPB + tid;
  const int rem = cell % (SG * SG);
  const float gx = (float)(rem % SG);   // xg varies along last spatial dim
  const float gy = (float)(rem / SG);   // yg varies along first spatial dim

  Box pa0, pa1, ta0, ta1;
  {
    float cx = (p[0] + gx) * STEPF, cy = (p[1] + gy) * STEPF, w = p[2], h = p[3];
    pa0 = {cx - 0.5f * w, cy - 0.5f * h, cx + 0.5f * w, cy + 0.5f * h};
    cx = (p[5] + gx) * STEPF; cy = (p[6] + gy) * STEPF; w = p[7]; h = p[8];
    pa1 = {cx - 0.5f * w, cy - 0.5f * h, cx + 0.5f * w, cy + 0.5f * h};
    cx = (t[0] + gx) * STEPF; cy = (t[1] + gy) * STEPF; w = t[2]; h = t[3];
    ta0 = {cx - 0.5f * w, cy - 0.5f * h, cx + 0.5f * w, cy + 0.5f * h};
    cx = (t[5] + gx) * STEPF; cy = (t[6] + gy) * STEPF; w = t[7]; h = t[8];
    ta1 = {cx - 0.5f * w, cy - 0.5f * h, cx + 0.5f * w, cy + 0.5f * h};
  }

  // responsibility: both pred boxes vs TARGET BOX 0; argmax first-wins
  const float iou0 = iou_fn(pa0, ta0);
  const float iou1 = iou_fn(pa1, ta0);
  const bool m1 = iou1 > iou0;
  const bool obj0 = (t[4] > 0.0f) && !m1;
  const bool obj1 = (t[9] > 0.0f) && m1;
  const bool sig = obj0 || obj1;

  const float d0 = p[4] - t[4], d1 = p[9] - t[9];
  const float se0 = d0 * d0, se1 = d1 * d1;
  const float obj_loss   = (obj0 ? se0 : 0.0f) + (obj1 ? se1 : 0.0f);
  const float noobj_loss = (obj0 ? 0.0f : se0) + (obj1 ? 0.0f : se1);

  // CIoU for the responsible pairing (pred box mi vs target box mi)
  Box b1, b2;
  b1.x1 = m1 ? pa1.x1 : pa0.x1; b1.y1 = m1 ? pa1.y1 : pa0.y1;
  b1.x2 = m1 ? pa1.x2 : pa0.x2; b1.y2 = m1 ? pa1.y2 : pa0.y2;
  b2.x1 = m1 ? ta1.x1 : ta0.x1; b2.y1 = m1 ? ta1.y1 : ta0.y1;
  b2.x2 = m1 ? ta1.x2 : ta0.x2; b2.y2 = m1 ? ta1.y2 : ta0.y2;

  float bbox;
  {
    const float iou = iou_fn(b1, b2);
    const float cx1 = 0.5f * (b1.x1 + b1.x2), cy1 = 0.5f * (b1.y1 + b1.y2);
    const float cx2 = 0.5f * (b2.x1 + b2.x2), cy2 = 0.5f * (b2.y1 + b2.y2);
    const float cd = (cx1 - cx2) * (cx1 - cx2) + (cy1 - cy2) * (cy1 - cy2);
    const float ox1 = fminf(b1.x1, b2.x1), oy1 = fminf(b1.y1, b2.y1);
    const float ox2 = fmaxf(b1.x2, b2.x2), oy2 = fmaxf(b1.y2, b2.y2);
    const float od = (ox2 - ox1) * (ox2 - ox1) + (oy2 - oy1) * (oy2 - oy1) + EPSF;
    const float w1 = fmaxf(b1.x2 - b1.x1, EPSF), h1 = fmaxf(b1.y2 - b1.y1, EPSF);
    const float w2 = fmaxf(b2.x2 - b2.x1, EPSF), h2 = fmaxf(b2.y2 - b2.y1, EPSF);
    const float dat = atanf(__fdividef(w2, h2)) - atanf(__fdividef(w1, h1));
    const float v = FOUR_OVER_PI2 * dat * dat;
    const float alpha = __fdividef(v, 1.0f - iou + v + EPSF);
    const float ciou = iou - __fdividef(cd, od) - alpha * v;
    const float scale = fmaxf(2.0f - w2 * h2, 1.0f);
    bbox = sig ? (1.0f - ciou) * scale : 0.0f;   // select AFTER: masks any NaN
  }

  float acc = obj_loss + L_NOOBJ * noobj_loss + L_COORD * bbox
            + (sig ? L_CLS * bce[tid] : 0.0f);

  // reduction: wave64 shuffle -> LDS -> one atomic per block
#pragma unroll
  for (int off = 32; off > 0; off >>= 1) acc += __shfl_down(acc, off);

  const int lane = tid & 63;
  const int wid  = tid >> 6;
  if (lane == 0) sdata[wid] = acc;
  __syncthreads();
  if (tid == 0) {
    const float s = sdata[0] + sdata[1] + sdata[2] + sdata[3];
    atomicAdd(out, s * INV_N);
  }
}

extern "C" void kernel_launch(void* const* d_in, const int* in_sizes, int n_in,
                              void* d_out, int out_size, void* d_ws, size_t ws_size,
                              hipStream_t stream) {
  const float* pred = (const float*)d_in[0];
  const float* tgt  = (const float*)d_in[1];
  float* out = (float*)d_out;

  // d_out is re-poisoned to 0xAA before every timed replay -> zero it here.
  hipMemsetAsync(out, 0, (size_t)out_size * sizeof(float), stream);

  const int blocks = NCELLS / CPB;   // 3136
  yolo_loss_kernel<<<blocks, CPB, 0, stream>>>(pred, tgt, out);
}

// Round 6
// 207.201 us; speedup vs baseline: 1.0545x; 1.0545x over previous
//
#include <hip/hip_runtime.h>
#include <math.h>

namespace {
constexpr int SG = 14;
constexpr int NCELLS = 4096 * SG * SG;      // 802816
constexpr int CPB = 64;                      // cells per (single-wave) block
constexpr int NBLK = NCELLS / CPB;           // 12544
constexpr int NBINS = 1024;
constexpr int BYTES_PER_BLK = CPB * 30 * 4;  // 7680 B per input per block
constexpr float STEPF = 1.0f / 14.0f;
constexpr float EPSF = 1e-6f;
constexpr float L_COORD = 7.0f;
constexpr float L_NOOBJ = 0.2f;
constexpr float L_CLS = 1.5f;
constexpr float INV_N = 1.0f / 4096.0f;
constexpr float FOUR_OVER_PI2 = 4.0f / (float)(M_PI * M_PI);
}

#define AS1 __attribute__((address_space(1)))
#define AS3 __attribute__((address_space(3)))

// async global->LDS: per-lane global src, wave-uniform LDS base (+lane*size)
__device__ __forceinline__ void gl_lds16(const void* g, void* l) {
  __builtin_amdgcn_global_load_lds((const AS1 unsigned int*)g, (AS3 unsigned int*)l, 16, 0, 0);
}
__device__ __forceinline__ void gl_lds4(const void* g, void* l) {
  __builtin_amdgcn_global_load_lds((const AS1 unsigned int*)g, (AS3 unsigned int*)l, 4, 0, 0);
}

struct Box { float x1, y1, x2, y2; };

__device__ __forceinline__ float iou_fn(const Box& a, const Box& b) {
  float ix1 = fmaxf(a.x1, b.x1);
  float iy1 = fmaxf(a.y1, b.y1);
  float ix2 = fminf(a.x2, b.x2);
  float iy2 = fminf(a.y2, b.y2);
  float inter = fmaxf(ix2 - ix1, 0.0f) * fmaxf(iy2 - iy1, 0.0f);
  float a1 = (a.x2 - a.x1) * (a.y2 - a.y1);
  float a2 = (b.x2 - b.x1) * (b.y2 - b.y1);
  return __fdividef(inter, a1 + a2 - inter + EPSF);
}

// BCE element; clip(log,-100) is lower-only. __logf(0) = -inf -> clamps to -100.
__device__ __forceinline__ float bce_term(float pc, float tc) {
  const float lg   = fmaxf(__logf(pc), -100.0f);
  const float l1mp = fmaxf(__logf(1.0f - pc), -100.0f);
  return -(tc * lg + (1.0f - tc) * l1mp);
}

__global__ __launch_bounds__(64) void yolo_k1(const float* __restrict__ pred,
                                              const float* __restrict__ tgt,
                                              float* __restrict__ bins) {
  // AoS slabs, staged linearly by the async copy (no transpose needed).
  __shared__ __align__(16) float pb[CPB * 30];   // 7680 B
  __shared__ __align__(16) float tb[CPB * 30];   // 7680 B -> 10 blocks/CU

  const int lane = threadIdx.x;
  const size_t base = (size_t)blockIdx.x * BYTES_PER_BLK;
  const char* gp = (const char*)pred + base;
  const char* gt = (const char*)tgt + base;
  char* lp = (char*)pb;
  char* lt = (char*)tb;

  // ---- issue ALL staging (18 async instrs, zero VGPR), single wait ----
#pragma unroll
  for (int j = 0; j < 7; ++j) {                 // 7 x 1024 B per input
    gl_lds16(gp + j * 1024 + lane * 16, lp + j * 1024);
    gl_lds16(gt + j * 1024 + lane * 16, lt + j * 1024);
  }
#pragma unroll
  for (int j = 0; j < 2; ++j) {                 // 512 B tail per input
    gl_lds4(gp + 7168 + j * 256 + lane * 4, lp + 7168 + j * 256);
    gl_lds4(gt + 7168 + j * 256 + lane * 4, lt + 7168 + j * 256);
  }
  asm volatile("s_waitcnt vmcnt(0)" ::: "memory");
  // single-wave block: own LDS writes visible after vmcnt(0); no barrier.

  // ---- per-cell compute: lane <-> cell, AoS reads from LDS ----
  const float2* pl = reinterpret_cast<const float2*>(pb + lane * 30);
  const float2* tl = reinterpret_cast<const float2*>(tb + lane * 30);

  float p[10], t[10];
#pragma unroll
  for (int k = 0; k < 5; ++k) {
    const float2 v = pl[k]; p[2 * k] = v.x; p[2 * k + 1] = v.y;
    const float2 u = tl[k]; t[2 * k] = u.x; t[2 * k + 1] = u.y;
  }

  const int cell = blockIdx.x * CPB + lane;
  const int rem = cell % (SG * SG);
  const float gx = (float)(rem % SG);
  const float gy = (float)(rem / SG);

  Box pa0, pa1, ta0, ta1;
  {
    float cx = (p[0] + gx) * STEPF, cy = (p[1] + gy) * STEPF, w = p[2], h = p[3];
    pa0 = {cx - 0.5f * w, cy - 0.5f * h, cx + 0.5f * w, cy + 0.5f * h};
    cx = (p[5] + gx) * STEPF; cy = (p[6] + gy) * STEPF; w = p[7]; h = p[8];
    pa1 = {cx - 0.5f * w, cy - 0.5f * h, cx + 0.5f * w, cy + 0.5f * h};
    cx = (t[0] + gx) * STEPF; cy = (t[1] + gy) * STEPF; w = t[2]; h = t[3];
    ta0 = {cx - 0.5f * w, cy - 0.5f * h, cx + 0.5f * w, cy + 0.5f * h};
    cx = (t[5] + gx) * STEPF; cy = (t[6] + gy) * STEPF; w = t[7]; h = t[8];
    ta1 = {cx - 0.5f * w, cy - 0.5f * h, cx + 0.5f * w, cy + 0.5f * h};
  }

  // responsibility: both pred boxes vs TARGET BOX 0; argmax first-wins
  const float iou0 = iou_fn(pa0, ta0);
  const float iou1 = iou_fn(pa1, ta0);
  const bool m1 = iou1 > iou0;
  const bool obj0 = (t[4] > 0.0f) && !m1;
  const bool obj1 = (t[9] > 0.0f) && m1;
  const bool sig = obj0 || obj1;

  const float d0 = p[4] - t[4], d1 = p[9] - t[9];
  const float se0 = d0 * d0, se1 = d1 * d1;
  const float obj_loss   = (obj0 ? se0 : 0.0f) + (obj1 ? se1 : 0.0f);
  const float noobj_loss = (obj0 ? 0.0f : se0) + (obj1 ? 0.0f : se1);

  // CIoU for the responsible pairing (pred box mi vs target box mi)
  Box b1, b2;
  b1.x1 = m1 ? pa1.x1 : pa0.x1; b1.y1 = m1 ? pa1.y1 : pa0.y1;
  b1.x2 = m1 ? pa1.x2 : pa0.x2; b1.y2 = m1 ? pa1.y2 : pa0.y2;
  b2.x1 = m1 ? ta1.x1 : ta0.x1; b2.y1 = m1 ? ta1.y1 : ta0.y1;
  b2.x2 = m1 ? ta1.x2 : ta0.x2; b2.y2 = m1 ? ta1.y2 : ta0.y2;

  float bbox;
  {
    const float iou = iou_fn(b1, b2);
    const float cx1 = 0.5f * (b1.x1 + b1.x2), cy1 = 0.5f * (b1.y1 + b1.y2);
    const float cx2 = 0.5f * (b2.x1 + b2.x2), cy2 = 0.5f * (b2.y1 + b2.y2);
    const float cd = (cx1 - cx2) * (cx1 - cx2) + (cy1 - cy2) * (cy1 - cy2);
    const float ox1 = fminf(b1.x1, b2.x1), oy1 = fminf(b1.y1, b2.y1);
    const float ox2 = fmaxf(b1.x2, b2.x2), oy2 = fmaxf(b1.y2, b2.y2);
    const float od = (ox2 - ox1) * (ox2 - ox1) + (oy2 - oy1) * (oy2 - oy1) + EPSF;
    const float w1 = fmaxf(b1.x2 - b1.x1, EPSF), h1 = fmaxf(b1.y2 - b1.y1, EPSF);
    const float w2 = fmaxf(b2.x2 - b2.x1, EPSF), h2 = fmaxf(b2.y2 - b2.y1, EPSF);
    const float dat = atanf(__fdividef(w2, h2)) - atanf(__fdividef(w1, h1));
    const float v = FOUR_OVER_PI2 * dat * dat;
    const float alpha = __fdividef(v, 1.0f - iou + v + EPSF);
    const float ciou = iou - __fdividef(cd, od) - alpha * v;
    const float scale = fmaxf(2.0f - w2 * h2, 1.0f);
    bbox = sig ? (1.0f - ciou) * scale : 0.0f;   // select AFTER: masks any NaN
  }

  // class BCE (20 classes) straight from LDS, 2 at a time
  float cls = 0.0f;
#pragma unroll
  for (int k = 0; k < 10; ++k) {
    const float2 v = pl[5 + k];
    const float2 u = tl[5 + k];
    cls += bce_term(v.x, u.x) + bce_term(v.y, u.y);
  }

  float acc = obj_loss + L_NOOBJ * noobj_loss + L_COORD * bbox
            + (sig ? L_CLS * cls : 0.0f);

  // wave64 reduce -> one atomic per wave into a spread bin
#pragma unroll
  for (int off = 32; off > 0; off >>= 1) acc += __shfl_down(acc, off);
  if (lane == 0) atomicAdd(&bins[blockIdx.x & (NBINS - 1)], acc);
}

__global__ __launch_bounds__(256) void yolo_k2(const float* __restrict__ bins,
                                               float* __restrict__ out) {
  const int tid = threadIdx.x;
  float s = bins[tid] + bins[tid + 256] + bins[tid + 512] + bins[tid + 768];
#pragma unroll
  for (int off = 32; off > 0; off >>= 1) s += __shfl_down(s, off);
  __shared__ float sd[4];
  if ((tid & 63) == 0) sd[tid >> 6] = s;
  __syncthreads();
  if (tid == 0) out[0] = (sd[0] + sd[1] + sd[2] + sd[3]) * INV_N;
}

extern "C" void kernel_launch(void* const* d_in, const int* in_sizes, int n_in,
                              void* d_out, int out_size, void* d_ws, size_t ws_size,
                              hipStream_t stream) {
  const float* pred = (const float*)d_in[0];
  const float* tgt  = (const float*)d_in[1];
  float* out  = (float*)d_out;
  float* bins = (float*)d_ws;            // 1024 floats of scratch (poisoned each replay)

  hipMemsetAsync(bins, 0, NBINS * sizeof(float), stream);
  yolo_k1<<<NBLK, CPB, 0, stream>>>(pred, tgt, bins);
  yolo_k2<<<1, 256, 0, stream>>>(bins, out);   // overwrites out -> no out memset needed
}